// Round 2
// baseline (381.696 us; speedup 1.0000x reference)
//
#include <hip/hip_runtime.h>
#include <stdint.h>

#define N_EX 131072
#define DIM 128
#define NC 8192
#define NW 8192
#define TEMP_INV 10.0f   // 1/temperature

typedef __attribute__((ext_vector_type(8))) __bf16 bf16x8;
typedef __attribute__((ext_vector_type(8))) unsigned short us8;
typedef __attribute__((ext_vector_type(4))) float f32x4;

__device__ __forceinline__ unsigned short f2bf(float f) {
    union { float f; unsigned u; } v; v.f = f;
    unsigned u = v.u;
    unsigned r = u + 0x7fffu + ((u >> 16) & 1u);  // round-nearest-even
    return (unsigned short)(r >> 16);
}
__device__ __forceinline__ float bf2f(unsigned lo16) {
    union { unsigned u; float f; } x; x.u = lo16 << 16; return x.f;
}

// ---------------------------------------------------------------- count + dedupe
__global__ void k_count(const int* __restrict__ cid, const int* __restrict__ wid,
                        int* cnt_c, int* cnt_w, unsigned* bitmask,
                        int* u_row, int* u_col, unsigned* pairs, int* n_unique) {
    int i = blockIdx.x * blockDim.x + threadIdx.x;
    if (i >= N_EX) return;
    int c = cid[i], w = wid[i];
    atomicAdd(&cnt_c[c], 1);
    atomicAdd(&cnt_w[w], 1);
    unsigned key = ((unsigned)c << 13) | (unsigned)w;   // c,w < 8192
    unsigned bit = 1u << (key & 31);
    unsigned old = atomicOr(&bitmask[key >> 5], bit);
    if (!(old & bit)) {   // first claimant owns this unique pair
        int p = atomicAdd(n_unique, 1);
        pairs[p] = key;
        atomicAdd(&u_row[c], 1);
        atomicAdd(&u_col[w], 1);
    }
}

// ---------------------------------------------------------------- exclusive scan (8192 ints), blockIdx.x selects side
__global__ void k_scan(const int* __restrict__ cnt_c, const int* __restrict__ cnt_w,
                       int* off_c, int* off_w, int* cur_c, int* cur_w) {
    const int* cnt = blockIdx.x ? cnt_w : cnt_c;
    int* offs = blockIdx.x ? off_w : off_c;
    int* cur  = blockIdx.x ? cur_w : cur_c;
    __shared__ int sh[1024];
    int t = threadIdx.x;          // 1024 threads, 8 elems each
    int loc[8]; int s = 0;
#pragma unroll
    for (int j = 0; j < 8; j++) { loc[j] = s; s += cnt[t * 8 + j]; }
    sh[t] = s; __syncthreads();
    for (int o = 1; o < 1024; o <<= 1) {
        int v = (t >= o) ? sh[t - o] : 0;
        __syncthreads();
        sh[t] += v;
        __syncthreads();
    }
    int pre = t ? sh[t - 1] : 0;
#pragma unroll
    for (int j = 0; j < 8; j++) { int v = pre + loc[j]; offs[t * 8 + j] = v; cur[t * 8 + j] = v; }
}

// ---------------------------------------------------------------- CSR scatter
__global__ void k_scatter(const int* __restrict__ cid, const int* __restrict__ wid,
                          int* cur_c, int* cur_w, int* rl_c, int* rl_w) {
    int i = blockIdx.x * blockDim.x + threadIdx.x;
    if (i < N_EX) {
        int c = cid[i]; int p = atomicAdd(&cur_c[c], 1); rl_c[p] = i;
    } else if (i < 2 * N_EX) {
        int j = i - N_EX; int w = wid[j]; int p = atomicAdd(&cur_w[w], 1); rl_w[p] = j;
    }
}

// ---------------------------------------------------------------- per-segment mean -> bf16 emb (csv side pre-scaled by 1/T)
__global__ void k_gather(const float* __restrict__ f1, const float* __restrict__ f2,
                         const int* __restrict__ off_c, const int* __restrict__ off_w,
                         const int* __restrict__ cnt_c, const int* __restrict__ cnt_w,
                         const int* __restrict__ rl_c, const int* __restrict__ rl_w,
                         unsigned short* emb_c, unsigned short* emb_w) {
    int seg = blockIdx.x, d = threadIdx.x;  // 128 threads = D
    const float* f = blockIdx.y ? f2 : f1;
    const int* off = blockIdx.y ? off_w : off_c;
    const int* cnt = blockIdx.y ? cnt_w : cnt_c;
    const int* rl  = blockIdx.y ? rl_w  : rl_c;
    unsigned short* emb = blockIdx.y ? emb_w : emb_c;
    int n = cnt[seg], o = off[seg];
    float s = 0.f;
    for (int j = 0; j < n; j++) s += f[(long)rl[o + j] * DIM + d];
    int dn = n > 1 ? n : 1;
    float scale = (blockIdx.y ? 1.0f : TEMP_INV) / (float)dn;
    emb[seg * DIM + d] = f2bf(s * scale);
}

// ---------------------------------------------------------------- bf16 MFMA GEMM + online-softmax partials
// 128x128 tile per block, 4 waves, each wave 64x64 as 4x4 grid of 16x16x32 mfma. K=128 preloaded.
// Each wave writes exact per-row / per-col (max, sumexp) partials for its 64x64 tile.
// rowpart: [8192 rows][128 slots] float2, slot = blockIdx.y*2 + (wid>>1)  -- race-free, fully written
// colpart: [8192 cols][128 slots] float2, slot = blockIdx.x*2 + (wid&1)
__global__ __launch_bounds__(256, 2) void k_gemm(const unsigned short* __restrict__ ea,
                                                 const unsigned short* __restrict__ eb,
                                                 float2* __restrict__ rowpart,
                                                 float2* __restrict__ colpart) {
    int tid = threadIdx.x;
    int lane = tid & 63, wid = tid >> 6;
    int q = lane >> 4, l15 = lane & 15;
    int rowhalf = wid & 1, colhalf = wid >> 1;
    int row0 = blockIdx.x * 128 + rowhalf * 64;
    int col0 = blockIdx.y * 128 + colhalf * 64;

    bf16x8 a[4][4], b[4][4];   // [m/n tile][k step]
#pragma unroll
    for (int t = 0; t < 4; t++)
#pragma unroll
        for (int s = 0; s < 4; s++) {
            // A[m=lane&15][k=q*8+j] ; B fed as wiki row (n=lane&15), same k layout (B^T usage)
            us8 av = *(const us8*)(ea + (long)(row0 + t * 16 + l15) * DIM + s * 32 + q * 8);
            us8 bv = *(const us8*)(eb + (long)(col0 + t * 16 + l15) * DIM + s * 32 + q * 8);
            a[t][s] = __builtin_bit_cast(bf16x8, av);
            b[t][s] = __builtin_bit_cast(bf16x8, bv);
        }

    f32x4 acc[4][4];
#pragma unroll
    for (int tm = 0; tm < 4; tm++)
#pragma unroll
        for (int tn = 0; tn < 4; tn++) acc[tm][tn] = (f32x4){0.f, 0.f, 0.f, 0.f};

#pragma unroll
    for (int s = 0; s < 4; s++)
#pragma unroll
        for (int tm = 0; tm < 4; tm++)
#pragma unroll
            for (int tn = 0; tn < 4; tn++)
                acc[tm][tn] = __builtin_amdgcn_mfma_f32_16x16x32_bf16(a[tm][s], b[tn][s], acc[tm][tn], 0, 0, 0);

    // D layout (m89-verified): col = lane&15, row = q*4 + reg
    // ---- per-row partials: row = row0 + tm*16 + q*4 + r; cols spread over l15 and tn
#pragma unroll
    for (int tm = 0; tm < 4; tm++) {
#pragma unroll
        for (int r = 0; r < 4; r++) {
            float m = acc[tm][0][r];
            m = fmaxf(m, acc[tm][1][r]);
            m = fmaxf(m, acc[tm][2][r]);
            m = fmaxf(m, acc[tm][3][r]);
            m = fmaxf(m, __shfl_xor(m, 1));
            m = fmaxf(m, __shfl_xor(m, 2));
            m = fmaxf(m, __shfl_xor(m, 4));
            m = fmaxf(m, __shfl_xor(m, 8));
            float s = 0.f;
#pragma unroll
            for (int tn = 0; tn < 4; tn++) s += __expf(acc[tm][tn][r] - m);
            s += __shfl_xor(s, 1); s += __shfl_xor(s, 2);
            s += __shfl_xor(s, 4); s += __shfl_xor(s, 8);
            if (l15 == 0) {
                int row = row0 + tm * 16 + q * 4 + r;
                rowpart[(long)row * 128 + blockIdx.y * 2 + colhalf] = make_float2(m, s);
            }
        }
    }
    // ---- per-col partials: col = col0 + tn*16 + l15; rows spread over q and (tm, r)
#pragma unroll
    for (int tn = 0; tn < 4; tn++) {
        float m = -1e30f;
#pragma unroll
        for (int tm = 0; tm < 4; tm++)
#pragma unroll
            for (int r = 0; r < 4; r++) m = fmaxf(m, acc[tm][tn][r]);
        m = fmaxf(m, __shfl_xor(m, 16));
        m = fmaxf(m, __shfl_xor(m, 32));
        float s = 0.f;
#pragma unroll
        for (int tm = 0; tm < 4; tm++)
#pragma unroll
            for (int r = 0; r < 4; r++) s += __expf(acc[tm][tn][r] - m);
        s += __shfl_xor(s, 16); s += __shfl_xor(s, 32);
        if (q == 0) {
            int col = col0 + tn * 16 + l15;
            colpart[(long)col * 128 + blockIdx.x * 2 + rowhalf] = make_float2(m, s);
        }
    }
}

// ---------------------------------------------------------------- combine 128 (max,sum) partials -> stable LSE
// one wave per row/col; 16384 waves total (first 8192 = rows, next 8192 = cols)
__global__ void k_combine(const float4* __restrict__ rowpart, const float4* __restrict__ colpart,
                          float* __restrict__ lse_row, float* __restrict__ lse_col) {
    int gtid = blockIdx.x * blockDim.x + threadIdx.x;
    int gw = gtid >> 6, lane = gtid & 63;
    int side = gw >> 13;
    int idx = gw & 8191;
    const float4* part = side ? colpart : rowpart;   // [8192][64] float4 view of [8192][128] float2
    float4 v = part[(long)idx * 64 + lane];
    float m = fmaxf(v.x, v.z);
    float s = v.y * __expf(v.x - m) + v.w * __expf(v.z - m);
#pragma unroll
    for (int o = 1; o < 64; o <<= 1) {
        float om = __shfl_xor(m, o), os = __shfl_xor(s, o);
        float M = fmaxf(m, om);
        s = s * __expf(m - M) + os * __expf(om - M);
        m = M;
    }
    if (lane == 0) {
        float* dst = side ? lse_col : lse_row;
        dst[idx] = m + logf(fmaxf(s, 1e-35f));
    }
}

// ---------------------------------------------------------------- masked logit sums over unique pairs (one wave per pair)
__global__ void k_pairs(const unsigned* __restrict__ pairs, const int* __restrict__ n_unique,
                        const unsigned short* __restrict__ ea, const unsigned short* __restrict__ eb,
                        float* S_row, float* S_col) {
    int gtid = blockIdx.x * blockDim.x + threadIdx.x;
    int wave = gtid >> 6, lane = gtid & 63;
    int nw = (gridDim.x * blockDim.x) >> 6;
    int M = *n_unique;
    for (int p = wave; p < M; p += nw) {
        unsigned key = pairs[p];
        int c = key >> 13, w = key & 8191;
        unsigned av = *(const unsigned*)(ea + c * DIM + lane * 2);
        unsigned bv = *(const unsigned*)(eb + w * DIM + lane * 2);
        float s = bf2f(av & 0xffffu) * bf2f(bv & 0xffffu) + bf2f(av >> 16) * bf2f(bv >> 16);
        s += __shfl_xor(s, 1); s += __shfl_xor(s, 2); s += __shfl_xor(s, 4);
        s += __shfl_xor(s, 8); s += __shfl_xor(s, 16); s += __shfl_xor(s, 32);
        if (lane == 0) { atomicAdd(&S_row[c], s); atomicAdd(&S_col[w], s); }
    }
}

// ---------------------------------------------------------------- final scalar
__global__ void k_final(const float* __restrict__ lse_row, const float* __restrict__ lse_col,
                        const float* __restrict__ S_row, const float* __restrict__ S_col,
                        const int* __restrict__ u_row, const int* __restrict__ u_col,
                        float* out) {
    __shared__ float sh[256];
    int t = threadIdx.x;
    float s1 = 0.f, s0 = 0.f;
    for (int c = t; c < NC; c += 256) {
        float U = (float)u_row[c];
        s1 += (S_row[c] - U * lse_row[c]) / fmaxf(U, 1.f);
    }
    for (int w = t; w < NW; w += 256) {
        float U = (float)u_col[w];
        s0 += (S_col[w] - U * lse_col[w]) / fmaxf(U, 1.f);
    }
    sh[t] = s1; __syncthreads();
    for (int o = 128; o > 0; o >>= 1) { if (t < o) sh[t] += sh[t + o]; __syncthreads(); }
    float tot1 = sh[0]; __syncthreads();
    sh[t] = s0; __syncthreads();
    for (int o = 128; o > 0; o >>= 1) { if (t < o) sh[t] += sh[t + o]; __syncthreads(); }
    if (t == 0) {
        float tot0 = sh[0];
        // loss = A0*axis0 + A1*axis1 = 0.5*(-tot0/W) + 0.5*(-tot1/C)
        out[0] = -0.5f * tot0 / (float)NW - 0.5f * tot1 / (float)NC;
    }
}

extern "C" void kernel_launch(void* const* d_in, const int* in_sizes, int n_in,
                              void* d_out, int out_size, void* d_ws, size_t ws_size,
                              hipStream_t stream) {
    const float* f1 = (const float*)d_in[0];
    const float* f2 = (const float*)d_in[1];
    const int* cid  = (const int*)d_in[2];
    const int* wid  = (const int*)d_in[3];
    float* out = (float*)d_out;

    char* ws = (char*)d_ws;
    size_t off = 0;
    auto alloc = [&](size_t bytes) -> void* {
        void* p = ws + off;
        off += (bytes + 255) & ~(size_t)255;
        return p;
    };
    // --- zero-initialized region (must be first; one memset) ---
    unsigned* bitmask = (unsigned*)alloc((size_t)NC * NW / 8);   // 8 MB
    int* cnt_c = (int*)alloc(NC * 4);
    int* cnt_w = (int*)alloc(NW * 4);
    int* u_row = (int*)alloc(NC * 4);
    int* u_col = (int*)alloc(NW * 4);
    float* S_row = (float*)alloc(NC * 4);
    float* S_col = (float*)alloc(NW * 4);
    int* n_unique = (int*)alloc(4);
    size_t zero_bytes = off;
    // --- non-zeroed scratch (fully written before read) ---
    int* off_c = (int*)alloc(NC * 4);
    int* off_w = (int*)alloc(NW * 4);
    int* cur_c = (int*)alloc(NC * 4);
    int* cur_w = (int*)alloc(NW * 4);
    int* rl_c = (int*)alloc((size_t)N_EX * 4);
    int* rl_w = (int*)alloc((size_t)N_EX * 4);
    unsigned* pairs = (unsigned*)alloc((size_t)N_EX * 4);
    unsigned short* emb_c = (unsigned short*)alloc((size_t)NC * DIM * 2);
    unsigned short* emb_w = (unsigned short*)alloc((size_t)NW * DIM * 2);
    float2* rowpart = (float2*)alloc((size_t)NC * 128 * sizeof(float2));  // 8 MB
    float2* colpart = (float2*)alloc((size_t)NW * 128 * sizeof(float2));  // 8 MB
    float* lse_row = (float*)alloc(NC * 4);
    float* lse_col = (float*)alloc(NW * 4);

    hipMemsetAsync(d_ws, 0, zero_bytes, stream);

    k_count<<<(N_EX + 255) / 256, 256, 0, stream>>>(cid, wid, cnt_c, cnt_w, bitmask,
                                                    u_row, u_col, pairs, n_unique);
    k_scan<<<2, 1024, 0, stream>>>(cnt_c, cnt_w, off_c, off_w, cur_c, cur_w);
    k_scatter<<<(2 * N_EX + 255) / 256, 256, 0, stream>>>(cid, wid, cur_c, cur_w, rl_c, rl_w);
    k_gather<<<dim3(NC, 2), 128, 0, stream>>>(f1, f2, off_c, off_w, cnt_c, cnt_w,
                                              rl_c, rl_w, emb_c, emb_w);
    k_gemm<<<dim3(NC / 128, NW / 128), 256, 0, stream>>>(emb_c, emb_w, rowpart, colpart);
    k_combine<<<(16384 * 64) / 256, 256, 0, stream>>>((const float4*)rowpart, (const float4*)colpart,
                                                      lse_row, lse_col);
    k_pairs<<<4096, 256, 0, stream>>>(pairs, n_unique, emb_c, emb_w, S_row, S_col);
    k_final<<<1, 256, 0, stream>>>(lse_row, lse_col, S_row, S_col, u_row, u_col, out);
}